// Round 1
// baseline (1801.295 us; speedup 1.0000x reference)
//
#include <hip/hip_runtime.h>
#include <hip/hip_bf16.h>

#define Vn   50000
#define NNZn 1600000
#define Bn   4
#define FINn 128
#define FOUTn 128
#define Kn   5
#define ROWF 512   // B*FIN features per vertex row

// ---------- bf16 helpers ----------
static __device__ __forceinline__ float bflo(unsigned u) { return __uint_as_float(u << 16); }
static __device__ __forceinline__ float bfhi(unsigned u) { return __uint_as_float(u & 0xffff0000u); }
static __device__ __forceinline__ unsigned short f2bf(float f) {
    unsigned u = __float_as_uint(f);
    u += 0x7fffu + ((u >> 16) & 1u);   // RNE
    return (unsigned short)(u >> 16);
}
static __device__ __forceinline__ unsigned pk2(float a, float b) {
    return (unsigned)f2bf(a) | ((unsigned)f2bf(b) << 16);
}
static __device__ __forceinline__ void fma8(float v, uint4 g, float* a) {
    a[0] += v * bflo(g.x); a[1] += v * bfhi(g.x);
    a[2] += v * bflo(g.y); a[3] += v * bfhi(g.y);
    a[4] += v * bflo(g.z); a[5] += v * bfhi(g.z);
    a[6] += v * bflo(g.w); a[7] += v * bfhi(g.w);
}

// ---------- CSR build ----------
__global__ __launch_bounds__(256) void zero_cnt_kernel(int* __restrict__ cnt) {
    int i = blockIdx.x * 256 + threadIdx.x;
    if (i < Vn) cnt[i] = 0;
}

__global__ __launch_bounds__(256) void hist_kernel(const int* __restrict__ rows, int* __restrict__ cnt) {
    int e = blockIdx.x * 256 + threadIdx.x;
    if (e < NNZn) atomicAdd(&cnt[rows[e]], 1);
}

// single-block scan: rp[i+1] = inclusive prefix; cnt[i] overwritten with exclusive prefix (scatter cursor)
__global__ __launch_bounds__(1024) void scan_kernel(int* __restrict__ cnt, int* __restrict__ rp) {
    __shared__ int buf[1024];
    __shared__ int carryS;
    int tid = threadIdx.x;
    if (tid == 0) { carryS = 0; rp[0] = 0; }
    __syncthreads();
    for (int base = 0; base < Vn; base += 4096) {
        int i0 = base + tid * 4;
        int x0 = 0, x1 = 0, x2 = 0, x3 = 0;
        if (i0 + 0 < Vn) x0 = cnt[i0 + 0];
        if (i0 + 1 < Vn) x1 = cnt[i0 + 1];
        if (i0 + 2 < Vn) x2 = cnt[i0 + 2];
        if (i0 + 3 < Vn) x3 = cnt[i0 + 3];
        int s = x0 + x1 + x2 + x3;
        buf[tid] = s;
        __syncthreads();
        for (int o = 1; o < 1024; o <<= 1) {
            int y = (tid >= o) ? buf[tid - o] : 0;
            __syncthreads();
            buf[tid] += y;
            __syncthreads();
        }
        int incl = buf[tid];
        int c = carryS;
        __syncthreads();
        int p = c + incl - s;  // exclusive prefix at i0
        if (i0 + 0 < Vn) { cnt[i0 + 0] = p; p += x0; rp[i0 + 1] = p; }
        if (i0 + 1 < Vn) { cnt[i0 + 1] = p; p += x1; rp[i0 + 2] = p; }
        if (i0 + 2 < Vn) { cnt[i0 + 2] = p; p += x2; rp[i0 + 3] = p; }
        if (i0 + 3 < Vn) { cnt[i0 + 3] = p; p += x3; rp[i0 + 4] = p; }
        if (tid == 1023) carryS = c + incl;
        __syncthreads();
    }
}

__global__ __launch_bounds__(256) void scatter_kernel(const int* __restrict__ rows, const int* __restrict__ cols,
                                                      const float* __restrict__ vals, int* __restrict__ cursor,
                                                      int* __restrict__ ci, float* __restrict__ cv) {
    int e = blockIdx.x * 256 + threadIdx.x;
    if (e < NNZn) {
        int r = rows[e];
        int p = atomicAdd(&cursor[r], 1);
        ci[p] = cols[e];
        cv[p] = vals[e];
    }
}

// ---------- transpose [B,V,FIN] fp32 -> x0 [V, B*FIN] bf16 ----------
__global__ __launch_bounds__(256) void transpose_kernel(const float* __restrict__ in, unsigned short* __restrict__ x0) {
    size_t t = (size_t)blockIdx.x * 256 + threadIdx.x;   // one thread = 8 fin elements
    if (t >= (size_t)Bn * Vn * 16) return;
    int f8 = (int)(t & 15);
    size_t bv = t >> 4;
    int v = (int)(bv % Vn);
    int b = (int)(bv / Vn);
    const float* src = in + bv * FINn + (size_t)f8 * 8;
    float4 s0 = *(const float4*)src;
    float4 s1 = *(const float4*)(src + 4);
    uint4 o;
    o.x = pk2(s0.x, s0.y); o.y = pk2(s0.z, s0.w);
    o.z = pk2(s1.x, s1.y); o.w = pk2(s1.z, s1.w);
    *(uint4*)(x0 + (size_t)v * ROWF + (size_t)b * FINn + (size_t)f8 * 8) = o;
}

// ---------- SPMM: xnew = (cheb ? 2*L*xprev - xpp : L*xprev), one wave per row ----------
__global__ __launch_bounds__(256) void spmm_kernel(const int* __restrict__ rp, const int* __restrict__ ci,
                                                   const float* __restrict__ cv,
                                                   const unsigned short* __restrict__ xprev,
                                                   const unsigned short* __restrict__ xpp,
                                                   unsigned short* __restrict__ xnew, int cheb) {
    int gw = (blockIdx.x * 256 + threadIdx.x) >> 6;   // wave id = vertex row
    if (gw >= Vn) return;
    int lane = threadIdx.x & 63;
    int s = rp[gw], e = rp[gw + 1];
    float a[8] = {0.f, 0.f, 0.f, 0.f, 0.f, 0.f, 0.f, 0.f};
    const unsigned short* gbase = xprev + (size_t)lane * 8;
    int i = s;
    for (; i + 2 <= e; i += 2) {
        int c0 = ci[i], c1 = ci[i + 1];
        float v0 = cv[i], v1 = cv[i + 1];
        uint4 g0 = *(const uint4*)(gbase + (size_t)c0 * ROWF);
        uint4 g1 = *(const uint4*)(gbase + (size_t)c1 * ROWF);
        fma8(v0, g0, a);
        fma8(v1, g1, a);
    }
    if (i < e) {
        int c0 = ci[i];
        float v0 = cv[i];
        uint4 g0 = *(const uint4*)(gbase + (size_t)c0 * ROWF);
        fma8(v0, g0, a);
    }
    if (cheb) {
        uint4 p = *(const uint4*)(xpp + (size_t)gw * ROWF + (size_t)lane * 8);
        a[0] = 2.f * a[0] - bflo(p.x); a[1] = 2.f * a[1] - bfhi(p.x);
        a[2] = 2.f * a[2] - bflo(p.y); a[3] = 2.f * a[3] - bfhi(p.y);
        a[4] = 2.f * a[4] - bflo(p.z); a[5] = 2.f * a[5] - bfhi(p.z);
        a[6] = 2.f * a[6] - bflo(p.w); a[7] = 2.f * a[7] - bfhi(p.w);
    }
    uint4 o;
    o.x = pk2(a[0], a[1]); o.y = pk2(a[2], a[3]);
    o.z = pk2(a[4], a[5]); o.w = pk2(a[6], a[7]);
    *(uint4*)(xnew + (size_t)gw * ROWF + (size_t)lane * 8) = o;
}

// ---------- GEMM: out[m,fo] (+)= sum_fin A[m,fin] * weight[(fin*5+k)*128+fo] ----------
// m = b*V+v; A row at xk + v*512 + b*128 (bf16). Block: 64 rows x 128 cols; thread: 8 rows x 4 cols.
__global__ __launch_bounds__(256) void gemm_kernel(const unsigned short* __restrict__ xk,
                                                   const float* __restrict__ weight,
                                                   const float* __restrict__ bias,
                                                   float* __restrict__ out, int k, int accmode) {
    __shared__ float As[64 * 8];    // [row][kk8]
    __shared__ float Ws[8 * 128];   // [kk8][fo]
    int tid = threadIdx.x;
    int m0 = blockIdx.x * 64;
    int ty = tid >> 5;          // 0..7 -> row group
    int tx = tid & 31;          // 0..31 -> col group (4 cols each)
    int ar = tid >> 2;          // staging: row 0..63
    int af = (tid & 3) * 2;     // staging: fin pair within 8

    const unsigned short* arow = nullptr;
    {
        int m = m0 + ar;
        if (m < Bn * Vn) {
            int b = m / Vn;
            int v = m - b * Vn;
            arow = xk + (size_t)v * ROWF + (size_t)b * FINn;
        }
    }

    float acc[8][4];
#pragma unroll
    for (int r = 0; r < 8; ++r) { acc[r][0] = acc[r][1] = acc[r][2] = acc[r][3] = 0.f; }

    for (int kk = 0; kk < FINn; kk += 8) {
        if (arow) {
            unsigned u = *(const unsigned*)(arow + kk + af);
            As[ar * 8 + af] = bflo(u);
            As[ar * 8 + af + 1] = bfhi(u);
        } else {
            As[ar * 8 + af] = 0.f;
            As[ar * 8 + af + 1] = 0.f;
        }
        {
            int fin = kk + ty;
            const float* wr = weight + (size_t)(fin * Kn + k) * FOUTn + (size_t)tx * 4;
            *(float4*)&Ws[ty * 128 + tx * 4] = *(const float4*)wr;
        }
        __syncthreads();
#pragma unroll
        for (int j = 0; j < 8; ++j) {
            float4 w = *(const float4*)&Ws[j * 128 + tx * 4];
#pragma unroll
            for (int r = 0; r < 8; ++r) {
                float av = As[(ty * 8 + r) * 8 + j];
                acc[r][0] += av * w.x;
                acc[r][1] += av * w.y;
                acc[r][2] += av * w.z;
                acc[r][3] += av * w.w;
            }
        }
        __syncthreads();
    }

    float4 b4 = *(const float4*)(bias + (size_t)tx * 4);
#pragma unroll
    for (int r = 0; r < 8; ++r) {
        int m = m0 + ty * 8 + r;
        if (m >= Bn * Vn) break;
        float* op = out + (size_t)m * FOUTn + (size_t)tx * 4;
        float4 val;
        val.x = acc[r][0]; val.y = acc[r][1]; val.z = acc[r][2]; val.w = acc[r][3];
        if (accmode) {
            float4 old = *(const float4*)op;
            val.x += old.x; val.y += old.y; val.z += old.z; val.w += old.w;
        } else {
            val.x += b4.x; val.y += b4.y; val.z += b4.z; val.w += b4.w;
        }
        *(float4*)op = val;
    }
}

extern "C" void kernel_launch(void* const* d_in, const int* in_sizes, int n_in,
                              void* d_out, int out_size, void* d_ws, size_t ws_size,
                              hipStream_t stream) {
    const int* lap_rows = (const int*)d_in[0];
    const int* lap_cols = (const int*)d_in[1];
    const float* lap_vals = (const float*)d_in[2];
    const float* inputs = (const float*)d_in[3];
    const float* weight = (const float*)d_in[4];
    const float* bias = (const float*)d_in[5];
    float* out = (float*)d_out;

    char* ws = (char*)d_ws;
    size_t off = 0;
    auto alloc = [&](size_t bytes) -> char* {
        char* p = ws + off;
        off += (bytes + 255) & ~(size_t)255;
        return p;
    };
    int* cnt = (int*)alloc((size_t)Vn * sizeof(int));          // histogram, then scatter cursor
    int* rp = (int*)alloc((size_t)(Vn + 1) * sizeof(int));
    int* ci = (int*)alloc((size_t)NNZn * sizeof(int));
    float* cv = (float*)alloc((size_t)NNZn * sizeof(float));
    unsigned short* xb0 = (unsigned short*)alloc((size_t)Vn * ROWF * 2);
    unsigned short* xb1 = (unsigned short*)alloc((size_t)Vn * ROWF * 2);
    unsigned short* xb2 = (unsigned short*)alloc((size_t)Vn * ROWF * 2);

    // CSR build
    zero_cnt_kernel<<<(Vn + 255) / 256, 256, 0, stream>>>(cnt);
    hist_kernel<<<(NNZn + 255) / 256, 256, 0, stream>>>(lap_rows, cnt);
    scan_kernel<<<1, 1024, 0, stream>>>(cnt, rp);
    scatter_kernel<<<(NNZn + 255) / 256, 256, 0, stream>>>(lap_rows, lap_cols, lap_vals, cnt, ci, cv);

    // x0 = transpose(inputs) -> bf16 [V, B*FIN]
    transpose_kernel<<<12500, 256, 0, stream>>>(inputs, xb0);

    const int spmm_blocks = (Vn * 64 + 255) / 256;   // one wave per row
    const int gemm_blocks = (Bn * Vn) / 64;          // 3125

    // k=0 contribution (writes out incl. bias)
    gemm_kernel<<<gemm_blocks, 256, 0, stream>>>(xb0, weight, bias, out, 0, 0);
    // x1 = L x0
    spmm_kernel<<<spmm_blocks, 256, 0, stream>>>(rp, ci, cv, xb0, xb0, xb1, 0);
    gemm_kernel<<<gemm_blocks, 256, 0, stream>>>(xb1, weight, bias, out, 1, 1);
    // x2 = 2 L x1 - x0
    spmm_kernel<<<spmm_blocks, 256, 0, stream>>>(rp, ci, cv, xb1, xb0, xb2, 1);
    gemm_kernel<<<gemm_blocks, 256, 0, stream>>>(xb2, weight, bias, out, 2, 1);
    // x3 = 2 L x2 - x1  (reuses xb0)
    spmm_kernel<<<spmm_blocks, 256, 0, stream>>>(rp, ci, cv, xb2, xb1, xb0, 1);
    gemm_kernel<<<gemm_blocks, 256, 0, stream>>>(xb0, weight, bias, out, 3, 1);
    // x4 = 2 L x3 - x2  (reuses xb1)
    spmm_kernel<<<spmm_blocks, 256, 0, stream>>>(rp, ci, cv, xb0, xb2, xb1, 1);
    gemm_kernel<<<gemm_blocks, 256, 0, stream>>>(xb1, weight, bias, out, 4, 1);
}

// Round 2
// 1573.009 us; speedup vs baseline: 1.1451x; 1.1451x over previous
//
#include <hip/hip_runtime.h>
#include <hip/hip_bf16.h>

#define Vn   50000
#define NNZn 1600000
#define Bn   4
#define FINn 128
#define FOUTn 128
#define Kn   5
#define ROWF 512   // B*FIN features per vertex row
#define Mtot (Bn * Vn)

typedef __attribute__((ext_vector_type(8))) short short8;
typedef __attribute__((ext_vector_type(4))) float f32x4;

// ---------- bf16 helpers ----------
static __device__ __forceinline__ float bflo(unsigned u) { return __uint_as_float(u << 16); }
static __device__ __forceinline__ float bfhi(unsigned u) { return __uint_as_float(u & 0xffff0000u); }
static __device__ __forceinline__ unsigned short f2bf(float f) {
    unsigned u = __float_as_uint(f);
    u += 0x7fffu + ((u >> 16) & 1u);   // RNE
    return (unsigned short)(u >> 16);
}
static __device__ __forceinline__ unsigned pk2(float a, float b) {
    return (unsigned)f2bf(a) | ((unsigned)f2bf(b) << 16);
}
static __device__ __forceinline__ void fma8(float v, uint4 g, float* a) {
    a[0] += v * bflo(g.x); a[1] += v * bfhi(g.x);
    a[2] += v * bflo(g.y); a[3] += v * bfhi(g.y);
    a[4] += v * bflo(g.z); a[5] += v * bfhi(g.z);
    a[6] += v * bflo(g.w); a[7] += v * bfhi(g.w);
}

// ---------- CSR build ----------
__global__ __launch_bounds__(256) void zero_cnt_kernel(int* __restrict__ cnt) {
    int i = blockIdx.x * 256 + threadIdx.x;
    if (i < Vn) cnt[i] = 0;
}

__global__ __launch_bounds__(256) void hist_kernel(const int* __restrict__ rows, int* __restrict__ cnt) {
    int e = blockIdx.x * 256 + threadIdx.x;
    if (e < NNZn) atomicAdd(&cnt[rows[e]], 1);
}

__global__ __launch_bounds__(1024) void scan_kernel(int* __restrict__ cnt, int* __restrict__ rp) {
    __shared__ int buf[1024];
    __shared__ int carryS;
    int tid = threadIdx.x;
    if (tid == 0) { carryS = 0; rp[0] = 0; }
    __syncthreads();
    for (int base = 0; base < Vn; base += 4096) {
        int i0 = base + tid * 4;
        int x0 = 0, x1 = 0, x2 = 0, x3 = 0;
        if (i0 + 0 < Vn) x0 = cnt[i0 + 0];
        if (i0 + 1 < Vn) x1 = cnt[i0 + 1];
        if (i0 + 2 < Vn) x2 = cnt[i0 + 2];
        if (i0 + 3 < Vn) x3 = cnt[i0 + 3];
        int s = x0 + x1 + x2 + x3;
        buf[tid] = s;
        __syncthreads();
        for (int o = 1; o < 1024; o <<= 1) {
            int y = (tid >= o) ? buf[tid - o] : 0;
            __syncthreads();
            buf[tid] += y;
            __syncthreads();
        }
        int incl = buf[tid];
        int c = carryS;
        __syncthreads();
        int p = c + incl - s;
        if (i0 + 0 < Vn) { cnt[i0 + 0] = p; p += x0; rp[i0 + 1] = p; }
        if (i0 + 1 < Vn) { cnt[i0 + 1] = p; p += x1; rp[i0 + 2] = p; }
        if (i0 + 2 < Vn) { cnt[i0 + 2] = p; p += x2; rp[i0 + 3] = p; }
        if (i0 + 3 < Vn) { cnt[i0 + 3] = p; p += x3; rp[i0 + 4] = p; }
        if (tid == 1023) carryS = c + incl;
        __syncthreads();
    }
}

__global__ __launch_bounds__(256) void scatter_kernel(const int* __restrict__ rows, const int* __restrict__ cols,
                                                      const float* __restrict__ vals, int* __restrict__ cursor,
                                                      int* __restrict__ ci, float* __restrict__ cv) {
    int e = blockIdx.x * 256 + threadIdx.x;
    if (e < NNZn) {
        int r = rows[e];
        int p = atomicAdd(&cursor[r], 1);
        ci[p] = cols[e];
        cv[p] = vals[e];
    }
}

// ---------- transpose [B,V,FIN] fp32 -> x0 [V, B*FIN] bf16 ----------
__global__ __launch_bounds__(256) void transpose_kernel(const float* __restrict__ in, unsigned short* __restrict__ x0) {
    size_t t = (size_t)blockIdx.x * 256 + threadIdx.x;
    if (t >= (size_t)Bn * Vn * 16) return;
    int f8 = (int)(t & 15);
    size_t bv = t >> 4;
    int v = (int)(bv % Vn);
    int b = (int)(bv / Vn);
    const float* src = in + bv * FINn + (size_t)f8 * 8;
    float4 s0 = *(const float4*)src;
    float4 s1 = *(const float4*)(src + 4);
    uint4 o;
    o.x = pk2(s0.x, s0.y); o.y = pk2(s0.z, s0.w);
    o.z = pk2(s1.x, s1.y); o.w = pk2(s1.z, s1.w);
    *(uint4*)(x0 + (size_t)v * ROWF + (size_t)b * FINn + (size_t)f8 * 8) = o;
}

// ---------- weight convert: wbfT[k][fo][fin] (bf16) = weightflat[(fin*5+k)*128+fo] ----------
__global__ __launch_bounds__(256) void wconv_kernel(const float* __restrict__ w, unsigned short* __restrict__ wbfT) {
    int t = blockIdx.x * 256 + threadIdx.x;
    if (t >= Kn * FOUTn * FINn) return;
    int fin = t & 127;
    int kn = t >> 7;
    int fo = kn & 127;
    int k = kn >> 7;
    wbfT[t] = f2bf(w[(size_t)(fin * Kn + k) * FOUTn + fo]);
}

// ---------- SPMM: xnew = (cheb ? 2*L*xprev - xpp : L*xprev), one wave per row ----------
__global__ __launch_bounds__(256) void spmm_kernel(const int* __restrict__ rp, const int* __restrict__ ci,
                                                   const float* __restrict__ cv,
                                                   const unsigned short* __restrict__ xprev,
                                                   const unsigned short* __restrict__ xpp,
                                                   unsigned short* __restrict__ xnew, int cheb) {
    int gw = (blockIdx.x * 256 + threadIdx.x) >> 6;
    if (gw >= Vn) return;
    int lane = threadIdx.x & 63;
    int s = rp[gw], e = rp[gw + 1];
    float a[8] = {0.f, 0.f, 0.f, 0.f, 0.f, 0.f, 0.f, 0.f};
    const unsigned short* gbase = xprev + (size_t)lane * 8;
    int i = s;
    for (; i + 4 <= e; i += 4) {
        int c0 = ci[i], c1 = ci[i + 1], c2 = ci[i + 2], c3 = ci[i + 3];
        float v0 = cv[i], v1 = cv[i + 1], v2 = cv[i + 2], v3 = cv[i + 3];
        uint4 g0 = *(const uint4*)(gbase + (size_t)c0 * ROWF);
        uint4 g1 = *(const uint4*)(gbase + (size_t)c1 * ROWF);
        uint4 g2 = *(const uint4*)(gbase + (size_t)c2 * ROWF);
        uint4 g3 = *(const uint4*)(gbase + (size_t)c3 * ROWF);
        fma8(v0, g0, a);
        fma8(v1, g1, a);
        fma8(v2, g2, a);
        fma8(v3, g3, a);
    }
    for (; i < e; ++i) {
        int c0 = ci[i];
        float v0 = cv[i];
        uint4 g0 = *(const uint4*)(gbase + (size_t)c0 * ROWF);
        fma8(v0, g0, a);
    }
    if (cheb) {
        uint4 p = *(const uint4*)(xpp + (size_t)gw * ROWF + (size_t)lane * 8);
        a[0] = 2.f * a[0] - bflo(p.x); a[1] = 2.f * a[1] - bfhi(p.x);
        a[2] = 2.f * a[2] - bflo(p.y); a[3] = 2.f * a[3] - bfhi(p.y);
        a[4] = 2.f * a[4] - bflo(p.z); a[5] = 2.f * a[5] - bfhi(p.z);
        a[6] = 2.f * a[6] - bflo(p.w); a[7] = 2.f * a[7] - bfhi(p.w);
    }
    uint4 o;
    o.x = pk2(a[0], a[1]); o.y = pk2(a[2], a[3]);
    o.z = pk2(a[4], a[5]); o.w = pk2(a[6], a[7]);
    *(uint4*)(xnew + (size_t)gw * ROWF + (size_t)lane * 8) = o;
}

// ---------- MFMA GEMM: out[m,fo] (+)= sum_j sum_fin A_j[m,fin] * wbfT[kbase+j][fo][fin] ----------
// Block: 128 rows x 128 cols, 256 threads (4 waves). Wave w: rows w*32..w*32+31, all 128 cols.
// LDS: As[128][128] bf16 + Ws[128][128] bf16 (W^T: [fo][fin]), XOR-swizzled in 16B chunks.
__global__ __launch_bounds__(256) void gemm_mfma_kernel(const unsigned short* __restrict__ s0,
                                                        const unsigned short* __restrict__ s1,
                                                        const unsigned short* __restrict__ s2,
                                                        const unsigned short* __restrict__ wbfT,
                                                        const float* __restrict__ bias,
                                                        float* __restrict__ out,
                                                        int kbase, int nsrc, int accmode) {
    __shared__ unsigned short As[128 * 128];
    __shared__ unsigned short Ws[128 * 128];
    int tid = threadIdx.x;
    int wave = tid >> 6, lane = tid & 63;
    int m0 = blockIdx.x * 128;
    int q = lane >> 4;        // 0..3
    int mr = lane & 15;       // 0..15

    f32x4 acc[2][8];
#pragma unroll
    for (int r = 0; r < 2; ++r)
#pragma unroll
        for (int n = 0; n < 8; ++n) acc[r][n] = (f32x4){0.f, 0.f, 0.f, 0.f};

    const unsigned short* srcs[3] = {s0, s1, s2};
    int sr = tid >> 1;        // staging row 0..127
    int sh = tid & 1;         // staging half

    for (int j = 0; j < nsrc; ++j) {
        // ---- stage A tile (swizzled: chunk ch of row r stored at ch^(r&7)) ----
        {
            int m = m0 + sr; if (m > Mtot - 1) m = Mtot - 1;
            int b = m / Vn, v = m - b * Vn;
            const uint4* gsrc = (const uint4*)(srcs[j] + (size_t)v * ROWF + (size_t)b * FINn + (size_t)sh * 64);
#pragma unroll
            for (int c = 0; c < 8; ++c) {
                int ch = sh * 8 + c;
                *(uint4*)(As + sr * 128 + ((ch ^ (sr & 7)) << 3)) = gsrc[c];
            }
        }
        // ---- stage W^T tile ----
        {
            const uint4* gsrc = (const uint4*)(wbfT + ((size_t)(kbase + j) * 128 + sr) * 128 + (size_t)sh * 64);
#pragma unroll
            for (int c = 0; c < 8; ++c) {
                int ch = sh * 8 + c;
                *(uint4*)(Ws + sr * 128 + ((ch ^ (sr & 7)) << 3)) = gsrc[c];
            }
        }
        __syncthreads();
        // ---- MFMA over K=128 ----
#pragma unroll
        for (int kk = 0; kk < 128; kk += 32) {
            int ch = (kk >> 3) + q;  // 16B chunk for this lane's k-slice
            int ra0 = wave * 32 + mr;
            int ra1 = wave * 32 + 16 + mr;
            short8 a0 = *(const short8*)(As + ra0 * 128 + ((ch ^ (ra0 & 7)) << 3));
            short8 a1 = *(const short8*)(As + ra1 * 128 + ((ch ^ (ra1 & 7)) << 3));
#pragma unroll
            for (int n = 0; n < 8; ++n) {
                int rb = n * 16 + mr;
                short8 bfr = *(const short8*)(Ws + rb * 128 + ((ch ^ (rb & 7)) << 3));
                acc[0][n] = __builtin_amdgcn_mfma_f32_16x16x32_bf16(a0, bfr, acc[0][n], 0, 0, 0);
                acc[1][n] = __builtin_amdgcn_mfma_f32_16x16x32_bf16(a1, bfr, acc[1][n], 0, 0, 0);
            }
        }
        __syncthreads();
    }

    // ---- epilogue: C/D layout col=lane&15, row=q*4+reg ----
#pragma unroll
    for (int rf = 0; rf < 2; ++rf) {
#pragma unroll
        for (int n = 0; n < 8; ++n) {
            int col = n * 16 + mr;
#pragma unroll
            for (int r = 0; r < 4; ++r) {
                int m = m0 + wave * 32 + rf * 16 + q * 4 + r;
                if (m < Mtot) {
                    float* op = out + (size_t)m * FOUTn + col;
                    float v = acc[rf][n][r];
                    if (accmode) v += *op;
                    else v += bias[col];
                    *op = v;
                }
            }
        }
    }
}

extern "C" void kernel_launch(void* const* d_in, const int* in_sizes, int n_in,
                              void* d_out, int out_size, void* d_ws, size_t ws_size,
                              hipStream_t stream) {
    const int* lap_rows = (const int*)d_in[0];
    const int* lap_cols = (const int*)d_in[1];
    const float* lap_vals = (const float*)d_in[2];
    const float* inputs = (const float*)d_in[3];
    const float* weight = (const float*)d_in[4];
    const float* bias = (const float*)d_in[5];
    float* out = (float*)d_out;

    char* ws = (char*)d_ws;
    size_t off = 0;
    auto alloc = [&](size_t bytes) -> char* {
        char* p = ws + off;
        off += (bytes + 255) & ~(size_t)255;
        return p;
    };
    int* cnt = (int*)alloc((size_t)Vn * sizeof(int));
    int* rp = (int*)alloc((size_t)(Vn + 1) * sizeof(int));
    int* ci = (int*)alloc((size_t)NNZn * sizeof(int));
    float* cv = (float*)alloc((size_t)NNZn * sizeof(float));
    unsigned short* xb0 = (unsigned short*)alloc((size_t)Vn * ROWF * 2);
    unsigned short* xb1 = (unsigned short*)alloc((size_t)Vn * ROWF * 2);
    unsigned short* xb2 = (unsigned short*)alloc((size_t)Vn * ROWF * 2);
    unsigned short* wbfT = (unsigned short*)alloc((size_t)Kn * FOUTn * FINn * 2);

    // CSR build
    zero_cnt_kernel<<<(Vn + 255) / 256, 256, 0, stream>>>(cnt);
    hist_kernel<<<(NNZn + 255) / 256, 256, 0, stream>>>(lap_rows, cnt);
    scan_kernel<<<1, 1024, 0, stream>>>(cnt, rp);
    scatter_kernel<<<(NNZn + 255) / 256, 256, 0, stream>>>(lap_rows, lap_cols, lap_vals, cnt, ci, cv);

    // weight convert + x0 transpose
    wconv_kernel<<<(Kn * FOUTn * FINn + 255) / 256, 256, 0, stream>>>(weight, wbfT);
    transpose_kernel<<<12500, 256, 0, stream>>>(inputs, xb0);

    const int spmm_blocks = (Vn * 64 + 255) / 256;
    const int gemm_blocks = (Mtot + 127) / 128;   // 1563

    // x1 = L x0
    spmm_kernel<<<spmm_blocks, 256, 0, stream>>>(rp, ci, cv, xb0, xb0, xb1, 0);
    // out = [x0,x1] @ [W0;W1] + bias
    gemm_mfma_kernel<<<gemm_blocks, 256, 0, stream>>>(xb0, xb1, xb1, wbfT, bias, out, 0, 2, 0);
    // x2 = 2 L x1 - x0
    spmm_kernel<<<spmm_blocks, 256, 0, stream>>>(rp, ci, cv, xb1, xb0, xb2, 1);
    // x3 = 2 L x2 - x1  (into xb0; x0 dead)
    spmm_kernel<<<spmm_blocks, 256, 0, stream>>>(rp, ci, cv, xb2, xb1, xb0, 1);
    // x4 = 2 L x3 - x2  (into xb1; x1 dead)
    spmm_kernel<<<spmm_blocks, 256, 0, stream>>>(rp, ci, cv, xb0, xb2, xb1, 1);
    // out += [x2,x3,x4] @ [W2;W3;W4]
    gemm_mfma_kernel<<<gemm_blocks, 256, 0, stream>>>(xb2, xb0, xb1, wbfT, bias, out, 2, 3, 1);
}

// Round 3
// 1106.241 us; speedup vs baseline: 1.6283x; 1.4219x over previous
//
#include <hip/hip_runtime.h>
#include <hip/hip_bf16.h>

#define Vn   50000
#define NNZn 1600000
#define Bn   4
#define FINn 128
#define FOUTn 128
#define Kn   5
#define ROWF 512   // B*FIN features per vertex row
#define Mtot (Bn * Vn)
#define NSCAN 13   // ceil(V/4096)

typedef __attribute__((ext_vector_type(8))) short short8;
typedef __attribute__((ext_vector_type(4))) float f32x4;
typedef __attribute__((ext_vector_type(2))) float f32x2;

// ---------- bf16 helpers ----------
static __device__ __forceinline__ float bflo(unsigned u) { return __uint_as_float(u << 16); }
static __device__ __forceinline__ float bfhi(unsigned u) { return __uint_as_float(u & 0xffff0000u); }
static __device__ __forceinline__ unsigned short f2bf(float f) {
    unsigned u = __float_as_uint(f);
    u += 0x7fffu + ((u >> 16) & 1u);   // RNE
    return (unsigned short)(u >> 16);
}
static __device__ __forceinline__ unsigned pk2(float a, float b) {
    return (unsigned)f2bf(a) | ((unsigned)f2bf(b) << 16);
}

// ---------- prep: zero cnt + weight convert + transpose(+fp8 mirror) in one launch ----------
// blocks [0,12500): transpose [B,V,FIN] fp32 -> xb0 bf16 [V,512] + f0 fp8 mirror
// blocks [12500,12820): wbfT[k][fo][fin] = bf16(weight[(fin*5+k)*128+fo])
// blocks [12820,13016): cnt[i] = 0
__global__ __launch_bounds__(256) void prep_kernel(const float* __restrict__ in,
                                                   unsigned short* __restrict__ x0,
                                                   unsigned char* __restrict__ x0f8,
                                                   const float* __restrict__ w,
                                                   unsigned short* __restrict__ wbfT,
                                                   int* __restrict__ cnt) {
    int bid = blockIdx.x;
    if (bid < 12500) {
        size_t t = (size_t)bid * 256 + threadIdx.x;      // exactly B*V*16 threads
        int f8 = (int)(t & 15);
        size_t bv = t >> 4;
        int v = (int)(bv % Vn);
        int b = (int)(bv / Vn);
        const float* src = in + bv * FINn + (size_t)f8 * 8;
        float4 s0 = *(const float4*)src;
        float4 s1 = *(const float4*)(src + 4);
        uint4 o;
        o.x = pk2(s0.x, s0.y); o.y = pk2(s0.z, s0.w);
        o.z = pk2(s1.x, s1.y); o.w = pk2(s1.z, s1.w);
        size_t doff = (size_t)v * ROWF + (size_t)b * FINn + (size_t)f8 * 8;
        *(uint4*)(x0 + doff) = o;
        int w0 = 0, w1 = 0;
        w0 = __builtin_amdgcn_cvt_pk_fp8_f32(s0.x, s0.y, w0, false);
        w0 = __builtin_amdgcn_cvt_pk_fp8_f32(s0.z, s0.w, w0, true);
        w1 = __builtin_amdgcn_cvt_pk_fp8_f32(s1.x, s1.y, w1, false);
        w1 = __builtin_amdgcn_cvt_pk_fp8_f32(s1.z, s1.w, w1, true);
        uint2 o8; o8.x = (unsigned)w0; o8.y = (unsigned)w1;
        *(uint2*)(x0f8 + doff) = o8;
    } else if (bid < 12820) {
        int t = (bid - 12500) * 256 + threadIdx.x;       // exactly 5*128*128
        int fin = t & 127;
        int kn = t >> 7;
        int fo = kn & 127;
        int k = kn >> 7;
        wbfT[t] = f2bf(w[(size_t)(fin * Kn + k) * FOUTn + fo]);
    } else {
        int i = (bid - 12820) * 256 + threadIdx.x;
        if (i < Vn) cnt[i] = 0;
    }
}

// ---------- CSR build ----------
__global__ __launch_bounds__(256) void hist_kernel(const int* __restrict__ rows, int* __restrict__ cnt) {
    int e = blockIdx.x * 256 + threadIdx.x;
    if (e < NNZn) atomicAdd(&cnt[rows[e]], 1);
}

// multi-block scan, step 1: per-block (4096 elems) exclusive scan into rp; block total -> bsum
__global__ __launch_bounds__(1024) void scan_part_kernel(const int* __restrict__ cnt,
                                                         int* __restrict__ rp, int* __restrict__ bsum) {
    __shared__ int buf[1024];
    int blk = blockIdx.x, tid = threadIdx.x;
    int i0 = blk * 4096 + tid * 4;
    int x0 = 0, x1 = 0, x2 = 0, x3 = 0;
    if (i0 + 0 < Vn) x0 = cnt[i0 + 0];
    if (i0 + 1 < Vn) x1 = cnt[i0 + 1];
    if (i0 + 2 < Vn) x2 = cnt[i0 + 2];
    if (i0 + 3 < Vn) x3 = cnt[i0 + 3];
    int s = x0 + x1 + x2 + x3;
    buf[tid] = s;
    __syncthreads();
    for (int o = 1; o < 1024; o <<= 1) {
        int y = (tid >= o) ? buf[tid - o] : 0;
        __syncthreads();
        buf[tid] += y;
        __syncthreads();
    }
    int incl = buf[tid];
    int p = incl - s;   // exclusive within block
    if (i0 + 0 < Vn) { rp[i0 + 0] = p; p += x0; }
    if (i0 + 1 < Vn) { rp[i0 + 1] = p; p += x1; }
    if (i0 + 2 < Vn) { rp[i0 + 2] = p; p += x2; }
    if (i0 + 3 < Vn) { rp[i0 + 3] = p; }
    if (tid == 1023) bsum[blk] = incl;
}

// step 2: exclusive scan of the NSCAN block sums (tiny, serial)
__global__ __launch_bounds__(64) void scan_tot_kernel(int* __restrict__ bsum) {
    if (threadIdx.x == 0 && blockIdx.x == 0) {
        int run = 0;
        for (int b = 0; b < NSCAN; ++b) { int t = bsum[b]; bsum[b] = run; run += t; }
    }
}

// step 3: add block offsets; produce final rp (row ptr) and cnt (scatter cursor); rp[V]=NNZ
__global__ __launch_bounds__(256) void scan_add_kernel(int* __restrict__ rp, int* __restrict__ cnt,
                                                       const int* __restrict__ bsum) {
    int i = blockIdx.x * 256 + threadIdx.x;
    if (i < Vn) {
        int v = rp[i] + bsum[i >> 12];
        rp[i] = v;
        cnt[i] = v;
    }
    if (i == 0) rp[Vn] = NNZn;
}

__global__ __launch_bounds__(256) void scatter_kernel(const int* __restrict__ rows, const int* __restrict__ cols,
                                                      const float* __restrict__ vals, int* __restrict__ cursor,
                                                      uint2* __restrict__ ecv) {
    int e = blockIdx.x * 256 + threadIdx.x;
    if (e < NNZn) {
        int r = rows[e];
        int p = atomicAdd(&cursor[r], 1);
        uint2 ev; ev.x = (unsigned)cols[e]; ev.y = __float_as_uint(vals[e]);
        ecv[p] = ev;
    }
}

// ---------- SPMM: xnew = (cheb ? 2*L*xprev - xpp : L*xprev); gather from fp8 mirror ----------
// one wave per row; lane i covers features [8i, 8i+8)
__global__ __launch_bounds__(256) void spmm_kernel(const int* __restrict__ rp, const uint2* __restrict__ ecv,
                                                   const unsigned char* __restrict__ f8prev,
                                                   const unsigned short* __restrict__ xpp,
                                                   unsigned short* __restrict__ xnew,
                                                   unsigned char* __restrict__ f8new,
                                                   int cheb, int wf8) {
    int gw = (blockIdx.x * 256 + threadIdx.x) >> 6;
    if (gw >= Vn) return;
    int lane = threadIdx.x & 63;
    int s = rp[gw], e = rp[gw + 1];
    f32x2 a0 = {0.f, 0.f}, a1 = {0.f, 0.f}, a2 = {0.f, 0.f}, a3 = {0.f, 0.f};
    const unsigned char* gbase = f8prev + (size_t)lane * 8;

#define ACCUM(g, vf)                                                             \
    {                                                                            \
        f32x2 vv = {vf, vf};                                                     \
        f32x2 p0 = __builtin_amdgcn_cvt_pk_f32_fp8((int)(g).x, false);           \
        f32x2 p1 = __builtin_amdgcn_cvt_pk_f32_fp8((int)(g).x, true);            \
        f32x2 p2 = __builtin_amdgcn_cvt_pk_f32_fp8((int)(g).y, false);           \
        f32x2 p3 = __builtin_amdgcn_cvt_pk_f32_fp8((int)(g).y, true);            \
        a0 += p0 * vv; a1 += p1 * vv; a2 += p2 * vv; a3 += p3 * vv;              \
    }

    int i = s;
    for (; i + 4 <= e; i += 4) {
        uint2 ec0 = ecv[i], ec1 = ecv[i + 1], ec2 = ecv[i + 2], ec3 = ecv[i + 3];
        uint2 g0 = *(const uint2*)(gbase + (size_t)ec0.x * ROWF);
        uint2 g1 = *(const uint2*)(gbase + (size_t)ec1.x * ROWF);
        uint2 g2 = *(const uint2*)(gbase + (size_t)ec2.x * ROWF);
        uint2 g3 = *(const uint2*)(gbase + (size_t)ec3.x * ROWF);
        ACCUM(g0, __uint_as_float(ec0.y));
        ACCUM(g1, __uint_as_float(ec1.y));
        ACCUM(g2, __uint_as_float(ec2.y));
        ACCUM(g3, __uint_as_float(ec3.y));
    }
    for (; i < e; ++i) {
        uint2 ec0 = ecv[i];
        uint2 g0 = *(const uint2*)(gbase + (size_t)ec0.x * ROWF);
        ACCUM(g0, __uint_as_float(ec0.y));
    }
#undef ACCUM

    if (cheb) {
        uint4 p = *(const uint4*)(xpp + (size_t)gw * ROWF + (size_t)lane * 8);
        f32x2 two = {2.f, 2.f};
        a0 = two * a0 - (f32x2){bflo(p.x), bfhi(p.x)};
        a1 = two * a1 - (f32x2){bflo(p.y), bfhi(p.y)};
        a2 = two * a2 - (f32x2){bflo(p.z), bfhi(p.z)};
        a3 = two * a3 - (f32x2){bflo(p.w), bfhi(p.w)};
    }
    size_t doff = (size_t)gw * ROWF + (size_t)lane * 8;
    uint4 o;
    o.x = pk2(a0.x, a0.y); o.y = pk2(a1.x, a1.y);
    o.z = pk2(a2.x, a2.y); o.w = pk2(a3.x, a3.y);
    *(uint4*)(xnew + doff) = o;
    if (wf8) {
        int w0 = 0, w1 = 0;
        w0 = __builtin_amdgcn_cvt_pk_fp8_f32(a0.x, a0.y, w0, false);
        w0 = __builtin_amdgcn_cvt_pk_fp8_f32(a1.x, a1.y, w0, true);
        w1 = __builtin_amdgcn_cvt_pk_fp8_f32(a2.x, a2.y, w1, false);
        w1 = __builtin_amdgcn_cvt_pk_fp8_f32(a3.x, a3.y, w1, true);
        uint2 o8; o8.x = (unsigned)w0; o8.y = (unsigned)w1;
        *(uint2*)(f8new + doff) = o8;
    }
}

// ---------- MFMA GEMM: out[m,fo] (+)= sum_j sum_fin A_j[m,fin] * wbfT[kbase+j][fo][fin] ----------
__global__ __launch_bounds__(256) void gemm_mfma_kernel(const unsigned short* __restrict__ s0,
                                                        const unsigned short* __restrict__ s1,
                                                        const unsigned short* __restrict__ s2,
                                                        const unsigned short* __restrict__ wbfT,
                                                        const float* __restrict__ bias,
                                                        float* __restrict__ out,
                                                        int kbase, int nsrc, int accmode) {
    __shared__ unsigned short As[128 * 128];
    __shared__ unsigned short Ws[128 * 128];
    int tid = threadIdx.x;
    int wave = tid >> 6, lane = tid & 63;
    int m0 = blockIdx.x * 128;
    int q = lane >> 4;
    int mr = lane & 15;

    f32x4 acc[2][8];
#pragma unroll
    for (int r = 0; r < 2; ++r)
#pragma unroll
        for (int n = 0; n < 8; ++n) acc[r][n] = (f32x4){0.f, 0.f, 0.f, 0.f};

    const unsigned short* srcs[3] = {s0, s1, s2};
    int sr = tid >> 1;
    int sh = tid & 1;

    for (int j = 0; j < nsrc; ++j) {
        {
            int m = m0 + sr; if (m > Mtot - 1) m = Mtot - 1;
            int b = m / Vn, v = m - b * Vn;
            const uint4* gsrc = (const uint4*)(srcs[j] + (size_t)v * ROWF + (size_t)b * FINn + (size_t)sh * 64);
#pragma unroll
            for (int c = 0; c < 8; ++c) {
                int ch = sh * 8 + c;
                *(uint4*)(As + sr * 128 + ((ch ^ (sr & 7)) << 3)) = gsrc[c];
            }
        }
        {
            const uint4* gsrc = (const uint4*)(wbfT + ((size_t)(kbase + j) * 128 + sr) * 128 + (size_t)sh * 64);
#pragma unroll
            for (int c = 0; c < 8; ++c) {
                int ch = sh * 8 + c;
                *(uint4*)(Ws + sr * 128 + ((ch ^ (sr & 7)) << 3)) = gsrc[c];
            }
        }
        __syncthreads();
#pragma unroll
        for (int kk = 0; kk < 128; kk += 32) {
            int ch = (kk >> 3) + q;
            int ra0 = wave * 32 + mr;
            int ra1 = wave * 32 + 16 + mr;
            short8 a0 = *(const short8*)(As + ra0 * 128 + ((ch ^ (ra0 & 7)) << 3));
            short8 a1 = *(const short8*)(As + ra1 * 128 + ((ch ^ (ra1 & 7)) << 3));
#pragma unroll
            for (int n = 0; n < 8; ++n) {
                int rb = n * 16 + mr;
                short8 bfr = *(const short8*)(Ws + rb * 128 + ((ch ^ (rb & 7)) << 3));
                acc[0][n] = __builtin_amdgcn_mfma_f32_16x16x32_bf16(a0, bfr, acc[0][n], 0, 0, 0);
                acc[1][n] = __builtin_amdgcn_mfma_f32_16x16x32_bf16(a1, bfr, acc[1][n], 0, 0, 0);
            }
        }
        __syncthreads();
    }

#pragma unroll
    for (int rf = 0; rf < 2; ++rf) {
#pragma unroll
        for (int n = 0; n < 8; ++n) {
            int col = n * 16 + mr;
#pragma unroll
            for (int r = 0; r < 4; ++r) {
                int m = m0 + wave * 32 + rf * 16 + q * 4 + r;
                if (m < Mtot) {
                    float* op = out + (size_t)m * FOUTn + col;
                    float v = acc[rf][n][r];
                    if (accmode) v += *op;
                    else v += bias[col];
                    *op = v;
                }
            }
        }
    }
}

extern "C" void kernel_launch(void* const* d_in, const int* in_sizes, int n_in,
                              void* d_out, int out_size, void* d_ws, size_t ws_size,
                              hipStream_t stream) {
    const int* lap_rows = (const int*)d_in[0];
    const int* lap_cols = (const int*)d_in[1];
    const float* lap_vals = (const float*)d_in[2];
    const float* inputs = (const float*)d_in[3];
    const float* weight = (const float*)d_in[4];
    const float* bias = (const float*)d_in[5];
    float* out = (float*)d_out;

    char* ws = (char*)d_ws;
    size_t off = 0;
    auto alloc = [&](size_t bytes) -> char* {
        char* p = ws + off;
        off += (bytes + 255) & ~(size_t)255;
        return p;
    };
    int* cnt = (int*)alloc((size_t)Vn * sizeof(int));
    int* rp = (int*)alloc((size_t)(Vn + 1) * sizeof(int));
    int* bsum = (int*)alloc((size_t)NSCAN * sizeof(int));
    uint2* ecv = (uint2*)alloc((size_t)NNZn * sizeof(uint2));
    unsigned short* xb0 = (unsigned short*)alloc((size_t)Vn * ROWF * 2);
    unsigned short* xb1 = (unsigned short*)alloc((size_t)Vn * ROWF * 2);
    unsigned short* xb2 = (unsigned short*)alloc((size_t)Vn * ROWF * 2);
    unsigned char* f0 = (unsigned char*)alloc((size_t)Vn * ROWF);
    unsigned char* f1 = (unsigned char*)alloc((size_t)Vn * ROWF);
    unsigned short* wbfT = (unsigned short*)alloc((size_t)Kn * FOUTn * FINn * 2);

    // prep: transpose+fp8 mirror | weight convert | zero cnt
    prep_kernel<<<13016, 256, 0, stream>>>(inputs, xb0, f0, weight, wbfT, cnt);
    // CSR build
    hist_kernel<<<(NNZn + 255) / 256, 256, 0, stream>>>(lap_rows, cnt);
    scan_part_kernel<<<NSCAN, 1024, 0, stream>>>(cnt, rp, bsum);
    scan_tot_kernel<<<1, 64, 0, stream>>>(bsum);
    scan_add_kernel<<<(Vn + 255) / 256, 256, 0, stream>>>(rp, cnt, bsum);
    scatter_kernel<<<(NNZn + 255) / 256, 256, 0, stream>>>(lap_rows, lap_cols, lap_vals, cnt, ecv);

    const int spmm_blocks = (Vn * 64 + 255) / 256;
    const int gemm_blocks = (Mtot + 127) / 128;

    // x1 = L x0
    spmm_kernel<<<spmm_blocks, 256, 0, stream>>>(rp, ecv, f0, xb0, xb1, f1, 0, 1);
    // out = [x0,x1] @ [W0;W1] + bias
    gemm_mfma_kernel<<<gemm_blocks, 256, 0, stream>>>(xb0, xb1, xb1, wbfT, bias, out, 0, 2, 0);
    // x2 = 2 L x1 - x0
    spmm_kernel<<<spmm_blocks, 256, 0, stream>>>(rp, ecv, f1, xb0, xb2, f0, 1, 1);
    // x3 = 2 L x2 - x1
    spmm_kernel<<<spmm_blocks, 256, 0, stream>>>(rp, ecv, f0, xb1, xb0, f1, 1, 1);
    // x4 = 2 L x3 - x2 (no fp8 mirror needed)
    spmm_kernel<<<spmm_blocks, 256, 0, stream>>>(rp, ecv, f1, xb2, xb1, f0, 1, 0);
    // out += [x2,x3,x4] @ [W2;W3;W4]
    gemm_mfma_kernel<<<gemm_blocks, 256, 0, stream>>>(xb2, xb0, xb1, wbfT, bias, out, 2, 3, 1);
}

// Round 4
// 1033.513 us; speedup vs baseline: 1.7429x; 1.0704x over previous
//
#include <hip/hip_runtime.h>
#include <hip/hip_bf16.h>

#define Vn   50000
#define NNZn 1600000
#define Bn   4
#define FINn 128
#define FOUTn 128
#define Kn   5
#define ROWF 512   // B*FIN features per vertex row
#define Mtot (Bn * Vn)
#define NSCAN 13   // ceil(V/4096)

typedef __attribute__((ext_vector_type(8))) short short8;
typedef __attribute__((ext_vector_type(4))) float f32x4;
typedef __attribute__((ext_vector_type(2))) float f32x2;

// ---------- bf16 helpers ----------
static __device__ __forceinline__ float bflo(unsigned u) { return __uint_as_float(u << 16); }
static __device__ __forceinline__ float bfhi(unsigned u) { return __uint_as_float(u & 0xffff0000u); }
static __device__ __forceinline__ unsigned short f2bf(float f) {
    unsigned u = __float_as_uint(f);
    u += 0x7fffu + ((u >> 16) & 1u);   // RNE
    return (unsigned short)(u >> 16);
}
static __device__ __forceinline__ unsigned pk2(float a, float b) {
    return (unsigned)f2bf(a) | ((unsigned)f2bf(b) << 16);
}

// ---------- prep: zero cnt + weight convert + transpose(+fp8 mirror) in one launch ----------
__global__ __launch_bounds__(256) void prep_kernel(const float* __restrict__ in,
                                                   unsigned short* __restrict__ x0,
                                                   unsigned char* __restrict__ x0f8,
                                                   const float* __restrict__ w,
                                                   unsigned short* __restrict__ wbfT,
                                                   int* __restrict__ cnt) {
    int bid = blockIdx.x;
    if (bid < 12500) {
        size_t t = (size_t)bid * 256 + threadIdx.x;      // exactly B*V*16 threads
        int f8 = (int)(t & 15);
        size_t bv = t >> 4;
        int v = (int)(bv % Vn);
        int b = (int)(bv / Vn);
        const float* src = in + bv * FINn + (size_t)f8 * 8;
        float4 s0 = *(const float4*)src;
        float4 s1 = *(const float4*)(src + 4);
        uint4 o;
        o.x = pk2(s0.x, s0.y); o.y = pk2(s0.z, s0.w);
        o.z = pk2(s1.x, s1.y); o.w = pk2(s1.z, s1.w);
        size_t doff = (size_t)v * ROWF + (size_t)b * FINn + (size_t)f8 * 8;
        *(uint4*)(x0 + doff) = o;
        int w0 = 0, w1 = 0;
        w0 = __builtin_amdgcn_cvt_pk_fp8_f32(s0.x, s0.y, w0, false);
        w0 = __builtin_amdgcn_cvt_pk_fp8_f32(s0.z, s0.w, w0, true);
        w1 = __builtin_amdgcn_cvt_pk_fp8_f32(s1.x, s1.y, w1, false);
        w1 = __builtin_amdgcn_cvt_pk_fp8_f32(s1.z, s1.w, w1, true);
        uint2 o8; o8.x = (unsigned)w0; o8.y = (unsigned)w1;
        *(uint2*)(x0f8 + doff) = o8;
    } else if (bid < 12820) {
        int t = (bid - 12500) * 256 + threadIdx.x;       // exactly 5*128*128
        int fin = t & 127;
        int kn = t >> 7;
        int fo = kn & 127;
        int k = kn >> 7;
        wbfT[t] = f2bf(w[(size_t)(fin * Kn + k) * FOUTn + fo]);
    } else {
        int i = (bid - 12820) * 256 + threadIdx.x;
        if (i < Vn) cnt[i] = 0;
    }
}

// ---------- CSR build ----------
__global__ __launch_bounds__(256) void hist_kernel(const int* __restrict__ rows, int* __restrict__ cnt) {
    int e = blockIdx.x * 256 + threadIdx.x;
    if (e < NNZn) atomicAdd(&cnt[rows[e]], 1);
}

__global__ __launch_bounds__(1024) void scan_part_kernel(const int* __restrict__ cnt,
                                                         int* __restrict__ rp, int* __restrict__ bsum) {
    __shared__ int buf[1024];
    int blk = blockIdx.x, tid = threadIdx.x;
    int i0 = blk * 4096 + tid * 4;
    int x0 = 0, x1 = 0, x2 = 0, x3 = 0;
    if (i0 + 0 < Vn) x0 = cnt[i0 + 0];
    if (i0 + 1 < Vn) x1 = cnt[i0 + 1];
    if (i0 + 2 < Vn) x2 = cnt[i0 + 2];
    if (i0 + 3 < Vn) x3 = cnt[i0 + 3];
    int s = x0 + x1 + x2 + x3;
    buf[tid] = s;
    __syncthreads();
    for (int o = 1; o < 1024; o <<= 1) {
        int y = (tid >= o) ? buf[tid - o] : 0;
        __syncthreads();
        buf[tid] += y;
        __syncthreads();
    }
    int incl = buf[tid];
    int p = incl - s;
    if (i0 + 0 < Vn) { rp[i0 + 0] = p; p += x0; }
    if (i0 + 1 < Vn) { rp[i0 + 1] = p; p += x1; }
    if (i0 + 2 < Vn) { rp[i0 + 2] = p; p += x2; }
    if (i0 + 3 < Vn) { rp[i0 + 3] = p; }
    if (tid == 1023) bsum[blk] = incl;
}

__global__ __launch_bounds__(64) void scan_tot_kernel(int* __restrict__ bsum) {
    if (threadIdx.x == 0 && blockIdx.x == 0) {
        int run = 0;
        for (int b = 0; b < NSCAN; ++b) { int t = bsum[b]; bsum[b] = run; run += t; }
    }
}

__global__ __launch_bounds__(256) void scan_add_kernel(int* __restrict__ rp, int* __restrict__ cnt,
                                                       const int* __restrict__ bsum) {
    int i = blockIdx.x * 256 + threadIdx.x;
    if (i < Vn) {
        int v = rp[i] + bsum[i >> 12];
        rp[i] = v;
        cnt[i] = v;
    }
    if (i == 0) rp[Vn] = NNZn;
}

__global__ __launch_bounds__(256) void scatter_kernel(const int* __restrict__ rows, const int* __restrict__ cols,
                                                      const float* __restrict__ vals, int* __restrict__ cursor,
                                                      uint2* __restrict__ ecv) {
    int e = blockIdx.x * 256 + threadIdx.x;
    if (e < NNZn) {
        int r = rows[e];
        int p = atomicAdd(&cursor[r], 1);
        uint2 ev; ev.x = (unsigned)cols[e]; ev.y = __float_as_uint(vals[e]);
        ecv[p] = ev;
    }
}

// ---------- SPMM: xnew = (cheb ? 2*L*xprev - xpp : L*xprev); gather from fp8 mirror ----------
__global__ __launch_bounds__(256) void spmm_kernel(const int* __restrict__ rp, const uint2* __restrict__ ecv,
                                                   const unsigned char* __restrict__ f8prev,
                                                   const unsigned short* __restrict__ xpp,
                                                   unsigned short* __restrict__ xnew,
                                                   unsigned char* __restrict__ f8new,
                                                   int cheb, int wf8) {
    int gw = (blockIdx.x * 256 + threadIdx.x) >> 6;
    if (gw >= Vn) return;
    int lane = threadIdx.x & 63;
    int s = rp[gw], e = rp[gw + 1];
    f32x2 a0 = {0.f, 0.f}, a1 = {0.f, 0.f}, a2 = {0.f, 0.f}, a3 = {0.f, 0.f};
    const unsigned char* gbase = f8prev + (size_t)lane * 8;

#define ACCUM(g, vf)                                                             \
    {                                                                            \
        f32x2 vv = {vf, vf};                                                     \
        f32x2 p0 = __builtin_amdgcn_cvt_pk_f32_fp8((int)(g).x, false);           \
        f32x2 p1 = __builtin_amdgcn_cvt_pk_f32_fp8((int)(g).x, true);            \
        f32x2 p2 = __builtin_amdgcn_cvt_pk_f32_fp8((int)(g).y, false);           \
        f32x2 p3 = __builtin_amdgcn_cvt_pk_f32_fp8((int)(g).y, true);            \
        a0 += p0 * vv; a1 += p1 * vv; a2 += p2 * vv; a3 += p3 * vv;              \
    }

    int i = s;
    for (; i + 4 <= e; i += 4) {
        uint2 ec0 = ecv[i], ec1 = ecv[i + 1], ec2 = ecv[i + 2], ec3 = ecv[i + 3];
        uint2 g0 = *(const uint2*)(gbase + (size_t)ec0.x * ROWF);
        uint2 g1 = *(const uint2*)(gbase + (size_t)ec1.x * ROWF);
        uint2 g2 = *(const uint2*)(gbase + (size_t)ec2.x * ROWF);
        uint2 g3 = *(const uint2*)(gbase + (size_t)ec3.x * ROWF);
        ACCUM(g0, __uint_as_float(ec0.y));
        ACCUM(g1, __uint_as_float(ec1.y));
        ACCUM(g2, __uint_as_float(ec2.y));
        ACCUM(g3, __uint_as_float(ec3.y));
    }
    for (; i < e; ++i) {
        uint2 ec0 = ecv[i];
        uint2 g0 = *(const uint2*)(gbase + (size_t)ec0.x * ROWF);
        ACCUM(g0, __uint_as_float(ec0.y));
    }
#undef ACCUM

    if (cheb) {
        uint4 p = *(const uint4*)(xpp + (size_t)gw * ROWF + (size_t)lane * 8);
        f32x2 two = {2.f, 2.f};
        a0 = two * a0 - (f32x2){bflo(p.x), bfhi(p.x)};
        a1 = two * a1 - (f32x2){bflo(p.y), bfhi(p.y)};
        a2 = two * a2 - (f32x2){bflo(p.z), bfhi(p.z)};
        a3 = two * a3 - (f32x2){bflo(p.w), bfhi(p.w)};
    }
    size_t doff = (size_t)gw * ROWF + (size_t)lane * 8;
    uint4 o;
    o.x = pk2(a0.x, a0.y); o.y = pk2(a1.x, a1.y);
    o.z = pk2(a2.x, a2.y); o.w = pk2(a3.x, a3.y);
    *(uint4*)(xnew + doff) = o;
    if (wf8) {
        int w0 = 0, w1 = 0;
        w0 = __builtin_amdgcn_cvt_pk_fp8_f32(a0.x, a0.y, w0, false);
        w0 = __builtin_amdgcn_cvt_pk_fp8_f32(a1.x, a1.y, w0, true);
        w1 = __builtin_amdgcn_cvt_pk_fp8_f32(a2.x, a2.y, w1, false);
        w1 = __builtin_amdgcn_cvt_pk_fp8_f32(a3.x, a3.y, w1, true);
        uint2 o8; o8.x = (unsigned)w0; o8.y = (unsigned)w1;
        *(uint2*)(f8new + doff) = o8;
    }
}

// ---------- MFMA GEMM v2: out[m,fo] (+)= sum_j sum_fin A_j[m,fin] * wbfT[kbase+j][fo][fin] ----------
// 64-row M-tile per block (M=200000 = 3125*64 exactly), 256 threads = 4 waves, each wave 16 rows.
// A: streamed directly global->fragment (16 full 64B cachelines per wave-load, no LDS).
// W: 32KB per hop staged PRE-FRAGMENTED in LDS: chunk C=(n*4+kc)*64+lane holds
//    wbfT[hop][fo=n*16+(lane&15)][k elems kc*32+(lane>>4)*8 .. +8]  (16B). Frag reads are
//    lane-consecutive 16B -> minimum bank pressure.
__global__ __launch_bounds__(256, 4) void gemm_mfma_kernel(const unsigned short* __restrict__ s0,
                                                           const unsigned short* __restrict__ s1,
                                                           const unsigned short* __restrict__ s2,
                                                           const unsigned short* __restrict__ wbfT,
                                                           const float* __restrict__ bias,
                                                           float* __restrict__ out,
                                                           int kbase, int nsrc, int accmode) {
    __shared__ unsigned short Wf[2048 * 8];   // 32 KB
    int tid = threadIdx.x;
    int wave = tid >> 6, lane = tid & 63;
    int q = lane >> 4, mr = lane & 15;
    int m0 = blockIdx.x * 64;
    int m = m0 + wave * 16 + mr;              // this lane's A row, always < Mtot
    int b = m / Vn, v = m - b * Vn;
    const size_t arow_off = (size_t)v * ROWF + (size_t)b * FINn;

    f32x4 acc[8];
#pragma unroll
    for (int n = 0; n < 8; ++n) acc[n] = (f32x4){0.f, 0.f, 0.f, 0.f};

    for (int j = 0; j < nsrc; ++j) {
        const unsigned short* src = (j == 0) ? s0 : (j == 1) ? s1 : s2;
        const unsigned short* wsrc = wbfT + (size_t)(kbase + j) * (FOUTn * FINn);
        // ---- stage W tile (pre-fragmented) ----
#pragma unroll
        for (int c = 0; c < 8; ++c) {
            int C = c * 256 + tid;
            int ln = C & 63;
            int kc = (C >> 6) & 3;
            int n = C >> 8;
            int fo = n * 16 + (ln & 15);
            int qq = ln >> 4;
            uint4 wv = *(const uint4*)(wsrc + (size_t)fo * FINn + kc * 32 + qq * 8);
            *(uint4*)(Wf + (size_t)C * 8) = wv;
        }
        __syncthreads();
        // ---- A fragments: this lane's full 128-fin row, 4 k-chunks ----
        const unsigned short* arow = src + arow_off;
        short8 a0 = *(const short8*)(arow + 0 * 32 + q * 8);
        short8 a1 = *(const short8*)(arow + 1 * 32 + q * 8);
        short8 a2 = *(const short8*)(arow + 2 * 32 + q * 8);
        short8 a3 = *(const short8*)(arow + 3 * 32 + q * 8);
        // ---- MFMA: 8 col-tiles x 4 k-steps ----
#pragma unroll
        for (int n = 0; n < 8; ++n) {
            short8 b0 = *(const short8*)(Wf + ((size_t)(n * 4 + 0) * 64 + lane) * 8);
            short8 b1 = *(const short8*)(Wf + ((size_t)(n * 4 + 1) * 64 + lane) * 8);
            short8 b2 = *(const short8*)(Wf + ((size_t)(n * 4 + 2) * 64 + lane) * 8);
            short8 b3 = *(const short8*)(Wf + ((size_t)(n * 4 + 3) * 64 + lane) * 8);
            acc[n] = __builtin_amdgcn_mfma_f32_16x16x32_bf16(a0, b0, acc[n], 0, 0, 0);
            acc[n] = __builtin_amdgcn_mfma_f32_16x16x32_bf16(a1, b1, acc[n], 0, 0, 0);
            acc[n] = __builtin_amdgcn_mfma_f32_16x16x32_bf16(a2, b2, acc[n], 0, 0, 0);
            acc[n] = __builtin_amdgcn_mfma_f32_16x16x32_bf16(a3, b3, acc[n], 0, 0, 0);
        }
        __syncthreads();
    }

    // ---- epilogue: D layout col=lane&15, row=q*4+reg ----
#pragma unroll
    for (int n = 0; n < 8; ++n) {
        int col = n * 16 + mr;
        float bcol = bias[col];
#pragma unroll
        for (int r = 0; r < 4; ++r) {
            int mrow = m0 + wave * 16 + q * 4 + r;
            float* op = out + (size_t)mrow * FOUTn + col;
            float vv = acc[n][r];
            if (accmode) vv += *op;
            else vv += bcol;
            *op = vv;
        }
    }
}

extern "C" void kernel_launch(void* const* d_in, const int* in_sizes, int n_in,
                              void* d_out, int out_size, void* d_ws, size_t ws_size,
                              hipStream_t stream) {
    const int* lap_rows = (const int*)d_in[0];
    const int* lap_cols = (const int*)d_in[1];
    const float* lap_vals = (const float*)d_in[2];
    const float* inputs = (const float*)d_in[3];
    const float* weight = (const float*)d_in[4];
    const float* bias = (const float*)d_in[5];
    float* out = (float*)d_out;

    char* ws = (char*)d_ws;
    size_t off = 0;
    auto alloc = [&](size_t bytes) -> char* {
        char* p = ws + off;
        off += (bytes + 255) & ~(size_t)255;
        return p;
    };
    int* cnt = (int*)alloc((size_t)Vn * sizeof(int));
    int* rp = (int*)alloc((size_t)(Vn + 1) * sizeof(int));
    int* bsum = (int*)alloc((size_t)NSCAN * sizeof(int));
    uint2* ecv = (uint2*)alloc((size_t)NNZn * sizeof(uint2));
    unsigned short* xb0 = (unsigned short*)alloc((size_t)Vn * ROWF * 2);
    unsigned short* xb1 = (unsigned short*)alloc((size_t)Vn * ROWF * 2);
    unsigned short* xb2 = (unsigned short*)alloc((size_t)Vn * ROWF * 2);
    unsigned char* f0 = (unsigned char*)alloc((size_t)Vn * ROWF);
    unsigned char* f1 = (unsigned char*)alloc((size_t)Vn * ROWF);
    unsigned short* wbfT = (unsigned short*)alloc((size_t)Kn * FOUTn * FINn * 2);

    // prep: transpose+fp8 mirror | weight convert | zero cnt
    prep_kernel<<<13016, 256, 0, stream>>>(inputs, xb0, f0, weight, wbfT, cnt);
    // CSR build
    hist_kernel<<<(NNZn + 255) / 256, 256, 0, stream>>>(lap_rows, cnt);
    scan_part_kernel<<<NSCAN, 1024, 0, stream>>>(cnt, rp, bsum);
    scan_tot_kernel<<<1, 64, 0, stream>>>(bsum);
    scan_add_kernel<<<(Vn + 255) / 256, 256, 0, stream>>>(rp, cnt, bsum);
    scatter_kernel<<<(NNZn + 255) / 256, 256, 0, stream>>>(lap_rows, lap_cols, lap_vals, cnt, ecv);

    const int spmm_blocks = (Vn * 64 + 255) / 256;
    const int gemm_blocks = Mtot / 64;   // 3125, exact

    // x1 = L x0
    spmm_kernel<<<spmm_blocks, 256, 0, stream>>>(rp, ecv, f0, xb0, xb1, f1, 0, 1);
    // out = [x0,x1] @ [W0;W1] + bias
    gemm_mfma_kernel<<<gemm_blocks, 256, 0, stream>>>(xb0, xb1, xb1, wbfT, bias, out, 0, 2, 0);
    // x2 = 2 L x1 - x0
    spmm_kernel<<<spmm_blocks, 256, 0, stream>>>(rp, ecv, f1, xb0, xb2, f0, 1, 1);
    // x3 = 2 L x2 - x1
    spmm_kernel<<<spmm_blocks, 256, 0, stream>>>(rp, ecv, f0, xb1, xb0, f1, 1, 1);
    // x4 = 2 L x3 - x2 (no fp8 mirror needed)
    spmm_kernel<<<spmm_blocks, 256, 0, stream>>>(rp, ecv, f1, xb2, xb1, f0, 1, 0);
    // out += [x2,x3,x4] @ [W2;W3;W4]
    gemm_mfma_kernel<<<gemm_blocks, 256, 0, stream>>>(xb2, xb0, xb1, wbfT, bias, out, 2, 3, 1);
}

// Round 5
// 935.522 us; speedup vs baseline: 1.9254x; 1.1047x over previous
//
#include <hip/hip_runtime.h>
#include <hip/hip_bf16.h>

#define Vn   50000
#define NNZn 1600000
#define Bn   4
#define FINn 128
#define FOUTn 128
#define Kn   5
#define ROWF 512   // B*FIN features per vertex row
#define Mtot (Bn * Vn)
#define NSCAN 13   // ceil(V/4096)

typedef __attribute__((ext_vector_type(8))) short short8;
typedef __attribute__((ext_vector_type(4))) float f32x4;
typedef __attribute__((ext_vector_type(2))) float f32x2;

// ---------- bf16 helpers ----------
static __device__ __forceinline__ float bflo(unsigned u) { return __uint_as_float(u << 16); }
static __device__ __forceinline__ float bfhi(unsigned u) { return __uint_as_float(u & 0xffff0000u); }
static __device__ __forceinline__ unsigned short f2bf(float f) {
    unsigned u = __float_as_uint(f);
    u += 0x7fffu + ((u >> 16) & 1u);   // RNE
    return (unsigned short)(u >> 16);
}
static __device__ __forceinline__ unsigned pk2(float a, float b) {
    return (unsigned)f2bf(a) | ((unsigned)f2bf(b) << 16);
}

// async global->LDS, 16B per lane; lds base must be wave-uniform, dest = base + lane*16
static __device__ __forceinline__ void gload_lds16(const unsigned short* g, unsigned short* l) {
    __builtin_amdgcn_global_load_lds((const __attribute__((address_space(1))) unsigned int*)g,
                                     (__attribute__((address_space(3))) unsigned int*)l, 16, 0, 0);
}

// ---------- prep: zero cnt + weight convert + transpose(+fp8 mirror) in one launch ----------
__global__ __launch_bounds__(256) void prep_kernel(const float* __restrict__ in,
                                                   unsigned short* __restrict__ x0,
                                                   unsigned char* __restrict__ x0f8,
                                                   const float* __restrict__ w,
                                                   unsigned short* __restrict__ wbfT,
                                                   int* __restrict__ cnt) {
    int bid = blockIdx.x;
    if (bid < 12500) {
        size_t t = (size_t)bid * 256 + threadIdx.x;      // exactly B*V*16 threads
        int f8 = (int)(t & 15);
        size_t bv = t >> 4;
        int v = (int)(bv % Vn);
        int b = (int)(bv / Vn);
        const float* src = in + bv * FINn + (size_t)f8 * 8;
        float4 s0 = *(const float4*)src;
        float4 s1 = *(const float4*)(src + 4);
        uint4 o;
        o.x = pk2(s0.x, s0.y); o.y = pk2(s0.z, s0.w);
        o.z = pk2(s1.x, s1.y); o.w = pk2(s1.z, s1.w);
        size_t doff = (size_t)v * ROWF + (size_t)b * FINn + (size_t)f8 * 8;
        *(uint4*)(x0 + doff) = o;
        int w0 = 0, w1 = 0;
        w0 = __builtin_amdgcn_cvt_pk_fp8_f32(s0.x, s0.y, w0, false);
        w0 = __builtin_amdgcn_cvt_pk_fp8_f32(s0.z, s0.w, w0, true);
        w1 = __builtin_amdgcn_cvt_pk_fp8_f32(s1.x, s1.y, w1, false);
        w1 = __builtin_amdgcn_cvt_pk_fp8_f32(s1.z, s1.w, w1, true);
        uint2 o8; o8.x = (unsigned)w0; o8.y = (unsigned)w1;
        *(uint2*)(x0f8 + doff) = o8;
    } else if (bid < 12820) {
        int t = (bid - 12500) * 256 + threadIdx.x;       // exactly 5*128*128
        int fin = t & 127;
        int kn = t >> 7;
        int fo = kn & 127;
        int k = kn >> 7;
        wbfT[t] = f2bf(w[(size_t)(fin * Kn + k) * FOUTn + fo]);
    } else {
        int i = (bid - 12820) * 256 + threadIdx.x;
        if (i < Vn) cnt[i] = 0;
    }
}

// ---------- CSR build ----------
__global__ __launch_bounds__(256) void hist_kernel(const int* __restrict__ rows, int* __restrict__ cnt) {
    int e = blockIdx.x * 256 + threadIdx.x;
    if (e < NNZn) atomicAdd(&cnt[rows[e]], 1);
}

__global__ __launch_bounds__(1024) void scan_part_kernel(const int* __restrict__ cnt,
                                                         int* __restrict__ rp, int* __restrict__ bsum) {
    __shared__ int buf[1024];
    int blk = blockIdx.x, tid = threadIdx.x;
    int i0 = blk * 4096 + tid * 4;
    int x0 = 0, x1 = 0, x2 = 0, x3 = 0;
    if (i0 + 0 < Vn) x0 = cnt[i0 + 0];
    if (i0 + 1 < Vn) x1 = cnt[i0 + 1];
    if (i0 + 2 < Vn) x2 = cnt[i0 + 2];
    if (i0 + 3 < Vn) x3 = cnt[i0 + 3];
    int s = x0 + x1 + x2 + x3;
    buf[tid] = s;
    __syncthreads();
    for (int o = 1; o < 1024; o <<= 1) {
        int y = (tid >= o) ? buf[tid - o] : 0;
        __syncthreads();
        buf[tid] += y;
        __syncthreads();
    }
    int incl = buf[tid];
    int p = incl - s;
    if (i0 + 0 < Vn) { rp[i0 + 0] = p; p += x0; }
    if (i0 + 1 < Vn) { rp[i0 + 1] = p; p += x1; }
    if (i0 + 2 < Vn) { rp[i0 + 2] = p; p += x2; }
    if (i0 + 3 < Vn) { rp[i0 + 3] = p; }
    if (tid == 1023) bsum[blk] = incl;
}

__global__ __launch_bounds__(64) void scan_tot_kernel(int* __restrict__ bsum) {
    if (threadIdx.x == 0 && blockIdx.x == 0) {
        int run = 0;
        for (int b = 0; b < NSCAN; ++b) { int t = bsum[b]; bsum[b] = run; run += t; }
    }
}

__global__ __launch_bounds__(256) void scan_add_kernel(int* __restrict__ rp, int* __restrict__ cnt,
                                                       const int* __restrict__ bsum) {
    int i = blockIdx.x * 256 + threadIdx.x;
    if (i < Vn) {
        int v = rp[i] + bsum[i >> 12];
        rp[i] = v;
        cnt[i] = v;
    }
    if (i == 0) rp[Vn] = NNZn;
}

__global__ __launch_bounds__(256) void scatter_kernel(const int* __restrict__ rows, const int* __restrict__ cols,
                                                      const float* __restrict__ vals, int* __restrict__ cursor,
                                                      uint2* __restrict__ ecv) {
    int e = blockIdx.x * 256 + threadIdx.x;
    if (e < NNZn) {
        int r = rows[e];
        int p = atomicAdd(&cursor[r], 1);
        uint2 ev; ev.x = (unsigned)cols[e]; ev.y = __float_as_uint(vals[e]);
        ecv[p] = ev;
    }
}

// ---------- SPMM: xnew = (cheb ? 2*L*xprev - xpp : L*xprev); gather from fp8 mirror ----------
__global__ __launch_bounds__(256) void spmm_kernel(const int* __restrict__ rp, const uint2* __restrict__ ecv,
                                                   const unsigned char* __restrict__ f8prev,
                                                   const unsigned short* __restrict__ xpp,
                                                   unsigned short* __restrict__ xnew,
                                                   unsigned char* __restrict__ f8new,
                                                   int cheb, int wf8) {
    int gw = (blockIdx.x * 256 + threadIdx.x) >> 6;
    if (gw >= Vn) return;
    int lane = threadIdx.x & 63;
    int s = rp[gw], e = rp[gw + 1];
    f32x2 a0 = {0.f, 0.f}, a1 = {0.f, 0.f}, a2 = {0.f, 0.f}, a3 = {0.f, 0.f};
    const unsigned char* gbase = f8prev + (size_t)lane * 8;

#define ACCUM(g, vf)                                                             \
    {                                                                            \
        f32x2 vv = {vf, vf};                                                     \
        f32x2 p0 = __builtin_amdgcn_cvt_pk_f32_fp8((int)(g).x, false);           \
        f32x2 p1 = __builtin_amdgcn_cvt_pk_f32_fp8((int)(g).x, true);            \
        f32x2 p2 = __builtin_amdgcn_cvt_pk_f32_fp8((int)(g).y, false);           \
        f32x2 p3 = __builtin_amdgcn_cvt_pk_f32_fp8((int)(g).y, true);            \
        a0 += p0 * vv; a1 += p1 * vv; a2 += p2 * vv; a3 += p3 * vv;              \
    }

    int i = s;
    for (; i + 4 <= e; i += 4) {
        uint2 ec0 = ecv[i], ec1 = ecv[i + 1], ec2 = ecv[i + 2], ec3 = ecv[i + 3];
        uint2 g0 = *(const uint2*)(gbase + (size_t)ec0.x * ROWF);
        uint2 g1 = *(const uint2*)(gbase + (size_t)ec1.x * ROWF);
        uint2 g2 = *(const uint2*)(gbase + (size_t)ec2.x * ROWF);
        uint2 g3 = *(const uint2*)(gbase + (size_t)ec3.x * ROWF);
        ACCUM(g0, __uint_as_float(ec0.y));
        ACCUM(g1, __uint_as_float(ec1.y));
        ACCUM(g2, __uint_as_float(ec2.y));
        ACCUM(g3, __uint_as_float(ec3.y));
    }
    for (; i < e; ++i) {
        uint2 ec0 = ecv[i];
        uint2 g0 = *(const uint2*)(gbase + (size_t)ec0.x * ROWF);
        ACCUM(g0, __uint_as_float(ec0.y));
    }
#undef ACCUM

    if (cheb) {
        uint4 p = *(const uint4*)(xpp + (size_t)gw * ROWF + (size_t)lane * 8);
        f32x2 two = {2.f, 2.f};
        a0 = two * a0 - (f32x2){bflo(p.x), bfhi(p.x)};
        a1 = two * a1 - (f32x2){bflo(p.y), bfhi(p.y)};
        a2 = two * a2 - (f32x2){bflo(p.z), bfhi(p.z)};
        a3 = two * a3 - (f32x2){bflo(p.w), bfhi(p.w)};
    }
    size_t doff = (size_t)gw * ROWF + (size_t)lane * 8;
    uint4 o;
    o.x = pk2(a0.x, a0.y); o.y = pk2(a1.x, a1.y);
    o.z = pk2(a2.x, a2.y); o.w = pk2(a3.x, a3.y);
    *(uint4*)(xnew + doff) = o;
    if (wf8) {
        int w0 = 0, w1 = 0;
        w0 = __builtin_amdgcn_cvt_pk_fp8_f32(a0.x, a0.y, w0, false);
        w0 = __builtin_amdgcn_cvt_pk_fp8_f32(a1.x, a1.y, w0, true);
        w1 = __builtin_amdgcn_cvt_pk_fp8_f32(a2.x, a2.y, w1, false);
        w1 = __builtin_amdgcn_cvt_pk_fp8_f32(a3.x, a3.y, w1, true);
        uint2 o8; o8.x = (unsigned)w0; o8.y = (unsigned)w1;
        *(uint2*)(f8new + doff) = o8;
    }
}

// ---------- MFMA GEMM v3: single pass over all 5 hops ----------
// out[m,fo] = bias[fo] + sum_{k=0..4} sum_fin x_k[m,fin] * wbfT[k][fo][fin]
// Block = 128 rows (2 tiles/wave), 256 threads. A: global->reg, double-buffered a hop ahead.
// W: global->LDS via global_load_lds, double-buffered (2x32KB), prefetched a hop ahead.
// One __syncthreads per hop. W pre-fragmented: chunk C=(n*4+kc)*64+lane (16B) holds
// wbfT[hop][fo=n*16+(lane&15)][kc*32+(lane>>4)*8 ..+8]; frag reads lane-consecutive 16B.
__global__ __launch_bounds__(256, 2) void gemm_mfma_kernel(const unsigned short* __restrict__ s0,
                                                           const unsigned short* __restrict__ s1,
                                                           const unsigned short* __restrict__ s2,
                                                           const unsigned short* __restrict__ s3,
                                                           const unsigned short* __restrict__ s4,
                                                           const unsigned short* __restrict__ wbfT,
                                                           const float* __restrict__ bias,
                                                           float* __restrict__ out) {
    __shared__ unsigned short Wf[2][2048 * 8];   // 2 x 32 KB
    int tid = threadIdx.x;
    int wave = tid >> 6, lane = tid & 63;
    int q = lane >> 4, mr = lane & 15;
    int m0 = blockIdx.x * 128;

    // this lane's two A-row offsets (clamped; stores are guarded)
    size_t aoff[2];
#pragma unroll
    for (int t = 0; t < 2; ++t) {
        int m = m0 + wave * 32 + t * 16 + mr;
        if (m > Mtot - 1) m = Mtot - 1;
        int b = m / Vn, v = m - b * Vn;
        aoff[t] = (size_t)v * ROWF + (size_t)b * FINn;
    }
    const unsigned short* srcs[5] = {s0, s1, s2, s3, s4};

    // acc init = bias (exact fp32 fold)
    f32x4 acc[2][8];
#pragma unroll
    for (int n = 0; n < 8; ++n) {
        float bc = bias[n * 16 + mr];
        f32x4 bi = {bc, bc, bc, bc};
        acc[0][n] = bi;
        acc[1][n] = bi;
    }

    // preload hop 0: W0 -> Wf[0] (async), A0 -> regs
#pragma unroll
    for (int c = 0; c < 8; ++c)
        gload_lds16(wbfT + (size_t)(c * 16 + mr) * FINn + wave * 32 + q * 8,
                    &Wf[0][(size_t)((c * 4 + wave) * 64) * 8]);
    short8 Acur[2][4], Anext[2][4];
#pragma unroll
    for (int t = 0; t < 2; ++t)
#pragma unroll
        for (int kc = 0; kc < 4; ++kc)
            Acur[t][kc] = *(const short8*)(s0 + aoff[t] + kc * 32 + q * 8);
    __syncthreads();

#pragma unroll
    for (int j = 0; j < 5; ++j) {
        if (j < 4) {
            // prefetch next hop's W (other LDS buffer) and A (regs) — in flight during MFMA
            const unsigned short* wsrc = wbfT + (size_t)(j + 1) * (FOUTn * FINn);
            unsigned short* dst = &Wf[(j + 1) & 1][0];
#pragma unroll
            for (int c = 0; c < 8; ++c)
                gload_lds16(wsrc + (size_t)(c * 16 + mr) * FINn + wave * 32 + q * 8,
                            dst + (size_t)((c * 4 + wave) * 64) * 8);
            const unsigned short* an = srcs[j + 1];
#pragma unroll
            for (int t = 0; t < 2; ++t)
#pragma unroll
                for (int kc = 0; kc < 4; ++kc)
                    Anext[t][kc] = *(const short8*)(an + aoff[t] + kc * 32 + q * 8);
        }
        const unsigned short* wb = &Wf[j & 1][0];
#pragma unroll
        for (int n = 0; n < 8; ++n) {
#pragma unroll
            for (int kc = 0; kc < 4; ++kc) {
                short8 bf = *(const short8*)(wb + (size_t)((n * 4 + kc) * 64 + lane) * 8);
                acc[0][n] = __builtin_amdgcn_mfma_f32_16x16x32_bf16(Acur[0][kc], bf, acc[0][n], 0, 0, 0);
                acc[1][n] = __builtin_amdgcn_mfma_f32_16x16x32_bf16(Acur[1][kc], bf, acc[1][n], 0, 0, 0);
            }
        }
        if (j < 4) {
#pragma unroll
            for (int t = 0; t < 2; ++t)
#pragma unroll
                for (int kc = 0; kc < 4; ++kc)
                    Acur[t][kc] = Anext[t][kc];
            __syncthreads();   // drains W(j+1)/A(j+1) loads; all waves done reading Wf[j&1]
        }
    }

    // epilogue: D layout col=lane&15, row=q*4+reg
#pragma unroll
    for (int t = 0; t < 2; ++t) {
#pragma unroll
        for (int n = 0; n < 8; ++n) {
            int col = n * 16 + mr;
#pragma unroll
            for (int r = 0; r < 4; ++r) {
                int m = m0 + wave * 32 + t * 16 + q * 4 + r;
                if (m < Mtot) out[(size_t)m * FOUTn + col] = acc[t][n][r];
            }
        }
    }
}

extern "C" void kernel_launch(void* const* d_in, const int* in_sizes, int n_in,
                              void* d_out, int out_size, void* d_ws, size_t ws_size,
                              hipStream_t stream) {
    const int* lap_rows = (const int*)d_in[0];
    const int* lap_cols = (const int*)d_in[1];
    const float* lap_vals = (const float*)d_in[2];
    const float* inputs = (const float*)d_in[3];
    const float* weight = (const float*)d_in[4];
    const float* bias = (const float*)d_in[5];
    float* out = (float*)d_out;

    char* ws = (char*)d_ws;
    size_t off = 0;
    auto alloc = [&](size_t bytes) -> char* {
        char* p = ws + off;
        off += (bytes + 255) & ~(size_t)255;
        return p;
    };
    int* cnt = (int*)alloc((size_t)Vn * sizeof(int));
    int* rp = (int*)alloc((size_t)(Vn + 1) * sizeof(int));
    int* bsum = (int*)alloc((size_t)NSCAN * sizeof(int));
    uint2* ecv = (uint2*)alloc((size_t)NNZn * sizeof(uint2));
    unsigned short* xb0 = (unsigned short*)alloc((size_t)Vn * ROWF * 2);
    unsigned short* xb1 = (unsigned short*)alloc((size_t)Vn * ROWF * 2);
    unsigned short* xb2 = (unsigned short*)alloc((size_t)Vn * ROWF * 2);
    unsigned short* xb3 = (unsigned short*)alloc((size_t)Vn * ROWF * 2);
    unsigned short* xb4 = (unsigned short*)alloc((size_t)Vn * ROWF * 2);
    unsigned char* f0 = (unsigned char*)alloc((size_t)Vn * ROWF);
    unsigned char* f1 = (unsigned char*)alloc((size_t)Vn * ROWF);
    unsigned short* wbfT = (unsigned short*)alloc((size_t)Kn * FOUTn * FINn * 2);

    // prep: transpose+fp8 mirror | weight convert | zero cnt
    prep_kernel<<<13016, 256, 0, stream>>>(inputs, xb0, f0, weight, wbfT, cnt);
    // CSR build
    hist_kernel<<<(NNZn + 255) / 256, 256, 0, stream>>>(lap_rows, cnt);
    scan_part_kernel<<<NSCAN, 1024, 0, stream>>>(cnt, rp, bsum);
    scan_tot_kernel<<<1, 64, 0, stream>>>(bsum);
    scan_add_kernel<<<(Vn + 255) / 256, 256, 0, stream>>>(rp, cnt, bsum);
    scatter_kernel<<<(NNZn + 255) / 256, 256, 0, stream>>>(lap_rows, lap_cols, lap_vals, cnt, ecv);

    const int spmm_blocks = (Vn * 64 + 255) / 256;
    const int gemm_blocks = (Mtot + 127) / 128;   // 1563

    // x1 = L x0
    spmm_kernel<<<spmm_blocks, 256, 0, stream>>>(rp, ecv, f0, xb0, xb1, f1, 0, 1);
    // x2 = 2 L x1 - x0   (f0's x0 mirror dead -> reuse for x2 mirror)
    spmm_kernel<<<spmm_blocks, 256, 0, stream>>>(rp, ecv, f1, xb0, xb2, f0, 1, 1);
    // x3 = 2 L x2 - x1   (f1 -> x3 mirror)
    spmm_kernel<<<spmm_blocks, 256, 0, stream>>>(rp, ecv, f0, xb1, xb3, f1, 1, 1);
    // x4 = 2 L x3 - x2   (no mirror needed)
    spmm_kernel<<<spmm_blocks, 256, 0, stream>>>(rp, ecv, f1, xb2, xb4, f0, 1, 0);
    // out = [x0..x4] @ [W0..W4] + bias  (single fused GEMM)
    gemm_mfma_kernel<<<gemm_blocks, 256, 0, stream>>>(xb0, xb1, xb2, xb3, xb4, wbfT, bias, out);
}